// Round 1
// baseline (1014.723 us; speedup 1.0000x reference)
//
#include <hip/hip_runtime.h>

#define IMG_H 2048
#define IMG_W 2048
#define WORDS32 64   // 32-bit words per row (2048 cols / 32)

// ---------------- Phase 1: global max (positive floats -> uint atomicMax) ----
__global__ void max_kernel(const float4* __restrict__ in, unsigned* __restrict__ maxout) {
    int tid = blockIdx.x * blockDim.x + threadIdx.x;
    int stride = gridDim.x * blockDim.x;
    float m = 0.0f;
    for (int i = tid; i < (IMG_H * IMG_W / 4); i += stride) {
        float4 v = in[i];
        m = fmaxf(fmaxf(m, v.x), fmaxf(v.y, fmaxf(v.z, v.w)));
    }
#pragma unroll
    for (int off = 32; off > 0; off >>= 1)
        m = fmaxf(m, __shfl_down(m, off, 64));
    if ((threadIdx.x & 63) == 0)
        atomicMax(maxout, __float_as_uint(m));
}

// ---------------- Phase 2: classify -> strong/weak bitmasks (ballot) --------
__global__ void binarize_kernel(const float* __restrict__ img,
                                const unsigned* __restrict__ maxbits,
                                unsigned long long* __restrict__ S,
                                unsigned long long* __restrict__ Wk) {
    int tid = blockIdx.x * blockDim.x + threadIdx.x;
    float maxv = __uint_as_float(*maxbits);
    float high = maxv * 0.15f;
    float low  = high * 0.05f;
    float x = img[tid];
    unsigned long long sb = __ballot(x > high);
    unsigned long long wb = __ballot((x >= low) && (x <= high));
    if ((threadIdx.x & 63) == 0) {
        S[tid >> 6]  = sb;
        Wk[tid >> 6] = wb;
    }
}

// ---------------- Phase 3: sequential raster scan, one wave, bit-parallel ---
// Row state: 2048 bits = 64 lanes x u32. Bit b of lane l = column l*32+b.
// Recurrence per row: x[j] = a[j] | (b[j] & x[j-1]) evaluated as a two-level
// Kogge-Stone closure (in-word shifts + ballot-based word-level scalar scan).
__global__ __launch_bounds__(64) void scan_kernel(const unsigned long long* __restrict__ Sg,
                                                  const unsigned long long* __restrict__ Wg,
                                                  unsigned long long* __restrict__ Ng) {
    const int lane = threadIdx.x;
    const unsigned* S32 = (const unsigned*)Sg;
    const unsigned* W32 = (const unsigned*)Wg;
    unsigned* N32 = (unsigned*)Ng;

    // rows 0 and 2047 are passed through unchanged
    unsigned s0 = S32[lane];
    N32[lane] = s0;
    N32[2047 * WORDS32 + lane] = S32[2047 * WORDS32 + lane];

    unsigned interior = 0xffffffffu;
    if (lane == 0)  interior &= ~1u;          // col 0 not interior
    if (lane == 63) interior &= 0x7fffffffu;  // col 2047 not interior

    unsigned ps = s0;                      // new-strong of previous row
    unsigned cs = S32[WORDS32 + lane];     // original strong of current row (row 1)
    unsigned long long cs_lsb = __ballot(cs & 1u);

    // software prefetch queue, depth 6 (2046 = 341 * 6 exactly)
    unsigned nsbuf[6], wkbuf[6];
#pragma unroll
    for (int u = 0; u < 6; ++u) {
        nsbuf[u] = S32[(2 + u) * WORDS32 + lane];
        wkbuf[u] = W32[(1 + u) * WORDS32 + lane];
    }

    for (int i = 1; i <= 2046; i += 6) {
#pragma unroll
        for (int u = 0; u < 6; ++u) {
            const int r = i + u;
            unsigned ns = nsbuf[u];
            unsigned wk = wkbuf[u];
            if (r + 6 <= 2046) {  // uniform guard; prefetch 6 rows ahead
                nsbuf[u] = S32[(r + 7) * WORDS32 + lane];
                wkbuf[u] = W32[(r + 6) * WORDS32 + lane];
            }
            unsigned b1 = wk & interior;

            // ---- ps-independent (off critical path) ----
            unsigned long long ns_lsb = __ballot(ns & 1u);
            unsigned long long ns_msb = __ballot(ns >> 31);

            // right(M)[j]=M[j+1]; left(M)[j]=M[j-1] (reference _shl/_shr resp.)
            unsigned rcs = (cs >> 1) | (((unsigned)((cs_lsb >> 1 >> lane) & 1ull)) << 31);
            unsigned rns = (ns >> 1) | (((unsigned)((ns_lsb >> 1 >> lane) & 1ull)) << 31);
            unsigned lns = (ns << 1) | ((unsigned)(((ns_msb << 1) >> lane) & 1ull));

            unsigned a_static = cs | (b1 & (rcs | lns | ns | rns));

            unsigned b2  = b1 & (b1 << 1);
            unsigned b4  = b2 & (b2 << 2);
            unsigned b8  = b4 & (b4 << 4);
            unsigned b16 = b8 & (b8 << 8);
            unsigned lowrun = b1 & (b1 ^ (b1 + 1u));  // low run of b1 from bit 0

            unsigned long long B1 = __ballot(b1 == 0xffffffffu);  // word is all-pass
            unsigned long long B2  = B1  & (B1  << 1);
            unsigned long long B4  = B2  & (B2  << 2);
            unsigned long long B8  = B4  & (B4  << 4);
            unsigned long long B16 = B8  & (B8  << 8);
            unsigned long long B32 = B16 & (B16 << 16);

            // ---- ps-dependent critical chain ----
            unsigned long long ps_msb = __ballot(ps >> 31);
            unsigned long long ps_lsb = __ballot(ps & 1u);
            unsigned lps = (ps << 1) | ((unsigned)(((ps_msb << 1) >> lane) & 1ull));
            unsigned rps = (ps >> 1) | (((unsigned)((ps_lsb >> 1 >> lane) & 1ull)) << 31);

            unsigned x = a_static | (b1 & (lps | ps | rps));
            // in-word closure (Kogge-Stone, 5 steps)
            x |= b1  & (x << 1);
            x |= b2  & (x << 2);
            x |= b4  & (x << 4);
            x |= b8  & (x << 8);
            x |= b16 & (x << 16);

            // word-level closure across 64 words (uniform, scalar ALU)
            unsigned long long A64 = __ballot(x >> 31);
            unsigned long long X = A64;
            X |= B1  & (X << 1);
            X |= B2  & (X << 2);
            X |= B4  & (X << 4);
            X |= B8  & (X << 8);
            X |= B16 & (X << 16);
            X |= B32 & (X << 32);

            unsigned carry = (unsigned)(((X << 1) >> lane) & 1ull);
            x |= (carry ? lowrun : 0u);

            // x == new strong mask of row r (non-weak positions reduce to cs)
            N32[r * WORDS32 + lane] = x;
            ps = x;
            cs = ns;
            cs_lsb = ns_lsb;
        }
    }
}

// ---------------- Phase 4: materialize fp32 output from masks ---------------
__global__ void expand_kernel(const unsigned long long* __restrict__ Ng,
                              const unsigned long long* __restrict__ Wg,
                              float4* __restrict__ out) {
    int tid = blockIdx.x * blockDim.x + threadIdx.x;
    int p = tid << 2;
    int row = p >> 11;
    int colbase = p & 2047;
    unsigned long long sw = Ng[p >> 6];
    unsigned long long ww = Wg[p >> 6];
    int bit = p & 63;
    bool edge = (row == 0) || (row == 2047);
    float4 o;
    float* po = (float*)&o;
#pragma unroll
    for (int k = 0; k < 4; ++k) {
        int b = bit + k;
        bool sn = (sw >> b) & 1ull;
        bool wb = (ww >> b) & 1ull;
        int col = colbase + k;
        bool keep25 = wb && (edge || col == 0 || col == 2047);
        po[k] = sn ? 255.0f : (keep25 ? 25.0f : 0.0f);
    }
    out[tid] = o;
}

extern "C" void kernel_launch(void* const* d_in, const int* in_sizes, int n_in,
                              void* d_out, int out_size, void* d_ws, size_t ws_size,
                              hipStream_t stream) {
    const float* img = (const float*)d_in[0];
    char* ws = (char*)d_ws;
    unsigned* maxbits = (unsigned*)ws;
    unsigned long long* S    = (unsigned long long*)(ws + 256);
    unsigned long long* Wk   = (unsigned long long*)(ws + 256 + (1 << 19));
    unsigned long long* Snew = (unsigned long long*)(ws + 256 + (1 << 20));

    hipMemsetAsync(d_ws, 0, 4, stream);  // zero the atomicMax cell

    max_kernel<<<1024, 256, 0, stream>>>((const float4*)img, maxbits);
    binarize_kernel<<<(IMG_H * IMG_W) / 256, 256, 0, stream>>>(img, maxbits, S, Wk);
    scan_kernel<<<1, 64, 0, stream>>>(S, Wk, Snew);
    expand_kernel<<<(IMG_H * IMG_W / 4) / 256, 256, 0, stream>>>(Snew, Wk, (float4*)d_out);
}

// Round 2
// 132.592 us; speedup vs baseline: 7.6529x; 7.6529x over previous
//
#include <hip/hip_runtime.h>

#define IMG_H 2048
#define IMG_W 2048
#define WPR 64       // 32-bit words per row
#define RSTRIPE 8
#define NSTRIPES 256 // covers rows 1..2046

typedef unsigned long long ull;

__device__ __forceinline__ unsigned interior_mask(int lane) {
    unsigned m = 0xffffffffu;
    if (lane == 0)  m &= ~1u;
    if (lane == 63) m &= 0x7fffffffu;
    return m;
}

struct RowCtx {
    unsigned b1, b2, b4, b8, b16, lowrun, a_static;
    ull B1, B2, B4, B8, B16, B32;
};

// ps-independent per-row precompute (shared between speculative chains)
__device__ __forceinline__ RowCtx make_ctx(unsigned cs, ull cs_lsb,
                                           unsigned ns, ull ns_lsb, ull ns_msb,
                                           unsigned wk, unsigned interior, int lane) {
    RowCtx c;
    c.b1 = wk & interior;
    unsigned rcs = (cs >> 1) | (((unsigned)((cs_lsb >> 1 >> lane) & 1ull)) << 31);
    unsigned rns = (ns >> 1) | (((unsigned)((ns_lsb >> 1 >> lane) & 1ull)) << 31);
    unsigned lns = (ns << 1) | ((unsigned)(((ns_msb << 1) >> lane) & 1ull));
    c.a_static = cs | (c.b1 & (rcs | lns | ns | rns));
    c.b2  = c.b1 & (c.b1 << 1);
    c.b4  = c.b2 & (c.b2 << 2);
    c.b8  = c.b4 & (c.b4 << 4);
    c.b16 = c.b8 & (c.b8 << 8);
    c.lowrun = c.b1 & (c.b1 ^ (c.b1 + 1u));   // low all-ones run of b1
    c.B1  = __ballot(c.b1 == 0xffffffffu);    // word fully propagates
    c.B2  = c.B1  & (c.B1  << 1);
    c.B4  = c.B2  & (c.B2  << 2);
    c.B8  = c.B4  & (c.B4  << 4);
    c.B16 = c.B8  & (c.B8  << 8);
    c.B32 = c.B16 & (c.B16 << 16);
    return c;
}

// one row of the recurrence: x[j] = a[j] | (b[j] & x[j-1]) closure, bit-parallel
__device__ __forceinline__ unsigned rowstep(unsigned ps, const RowCtx& c, int lane) {
    ull ps_msb = __ballot(ps >> 31);
    ull ps_lsb = __ballot(ps & 1u);
    unsigned lps = (ps << 1) | ((unsigned)(((ps_msb << 1) >> lane) & 1ull));
    unsigned rps = (ps >> 1) | (((unsigned)((ps_lsb >> 1 >> lane) & 1ull)) << 31);
    unsigned x = c.a_static | (c.b1 & (lps | ps | rps));
    x |= c.b1  & (x << 1);
    x |= c.b2  & (x << 2);
    x |= c.b4  & (x << 4);
    x |= c.b8  & (x << 8);
    x |= c.b16 & (x << 16);
    ull X = __ballot(x >> 31);
    X |= c.B1  & (X << 1);
    X |= c.B2  & (X << 2);
    X |= c.B4  & (X << 4);
    X |= c.B8  & (X << 8);
    X |= c.B16 & (X << 16);
    X |= c.B32 & (X << 32);
    unsigned carry = (unsigned)(((X << 1) >> lane) & 1ull);
    x |= carry ? c.lowrun : 0u;
    return x;
}

// ---------------- Phase 1: global max ----------------
__global__ void max_kernel(const float4* __restrict__ in, unsigned* __restrict__ maxout) {
    int tid = blockIdx.x * blockDim.x + threadIdx.x;
    int stride = gridDim.x * blockDim.x;
    float m = 0.0f;
    for (int i = tid; i < (IMG_H * IMG_W / 4); i += stride) {
        float4 v = in[i];
        m = fmaxf(fmaxf(m, v.x), fmaxf(v.y, fmaxf(v.z, v.w)));
    }
#pragma unroll
    for (int off = 32; off > 0; off >>= 1)
        m = fmaxf(m, __shfl_down(m, off, 64));
    if ((threadIdx.x & 63) == 0)
        atomicMax(maxout, __float_as_uint(m));
}

// ---------------- Phase 2: classify -> bitmasks ----------------
__global__ void binarize_kernel(const float* __restrict__ img,
                                const unsigned* __restrict__ maxbits,
                                ull* __restrict__ S, ull* __restrict__ Wk) {
    int tid = blockIdx.x * blockDim.x + threadIdx.x;
    float maxv = __uint_as_float(*maxbits);
    float high = maxv * 0.15f;
    float low  = high * 0.05f;
    float x = img[tid];
    ull sb = __ballot(x > high);
    ull wb = __ballot((x >= low) && (x <= high));
    if ((threadIdx.x & 63) == 0) {
        S[tid >> 6]  = sb;
        Wk[tid >> 6] = wb;
    }
}

// ---------------- Phase 3a: parallel speculative stripes ----------------
// Each block handles RSTRIPE rows with lower (ps=S[prev]) and upper
// (ps=S[prev]|W[prev]&interior) bounds. Monotonicity => first row where
// bounds agree is exact; all later rows in the stripe are exact.
__global__ __launch_bounds__(64) void spec_kernel(const unsigned* __restrict__ S32,
                                                  const unsigned* __restrict__ W32,
                                                  unsigned* __restrict__ N32,
                                                  int* __restrict__ conv) {
    const int s = blockIdx.x;
    const int lane = threadIdx.x;
    const int start = 1 + RSTRIPE * s;
    const int end = min(start + RSTRIPE, 2047);  // exclusive
    const unsigned interior = interior_mask(lane);

    // preload whole stripe (independent loads, one latency)
    unsigned pcs = S32[(start - 1) * WPR + lane];
    unsigned pw  = W32[(start - 1) * WPR + lane];
    unsigned csb[RSTRIPE + 1], wkb[RSTRIPE];
#pragma unroll
    for (int u = 0; u <= RSTRIPE; ++u)
        csb[u] = S32[min(start + u, 2047) * WPR + lane];
#pragma unroll
    for (int u = 0; u < RSTRIPE; ++u)
        wkb[u] = W32[min(start + u, 2046) * WPR + lane];

    unsigned psl = pcs;
    unsigned psu = (start == 1) ? pcs : (pcs | (pw & interior));  // row 0 is exact
    unsigned cs = csb[0];
    ull cs_lsb = __ballot(cs & 1u);
    int conv_r = end;           // sentinel: nothing exact in stripe
    bool converged = false;
#pragma unroll
    for (int u = 0; u < RSTRIPE; ++u) {
        const int r = start + u;
        if (r < 2047) {                       // uniform guard
            unsigned ns = csb[u + 1];
            unsigned wk = wkb[u];
            ull ns_lsb = __ballot(ns & 1u);
            ull ns_msb = __ballot(ns >> 31);
            RowCtx c = make_ctx(cs, cs_lsb, ns, ns_lsb, ns_msb, wk, interior, lane);
            unsigned xu = rowstep(psu, c, lane);
            unsigned xl;
            if (!converged) {                 // uniform
                xl = rowstep(psl, c, lane);
                if (__ballot(xl != xu) == 0ull) { converged = true; conv_r = r; }
            } else {
                xl = xu;
            }
            N32[r * WPR + lane] = xu;
            psl = xl;
            psu = xu;
            cs = ns;
            cs_lsb = ns_lsb;
        }
    }
    if (lane == 0) conv[s] = conv_r;
}

// ---------------- Phase 3b: sequential fix-up of unconverged prefixes -------
__global__ __launch_bounds__(64) void fix_kernel(const unsigned* __restrict__ S32,
                                                 const unsigned* __restrict__ W32,
                                                 unsigned* N32,
                                                 const int* __restrict__ conv) {
    const int lane = threadIdx.x;
    const unsigned interior = interior_mask(lane);
    for (int g = 0; g < NSTRIPES / 64; ++g) {
        int s = g * 64 + lane;
        int start0 = 1 + RSTRIPE * s;
        int cv = conv[s];
        ull bad = __ballot(cv > start0);
        while (bad) {                         // uniform loop, ascending order
            int idx = __ffsll(bad) - 1;
            bad &= bad - 1;
            int bs = g * 64 + idx;
            int bstart = 1 + RSTRIPE * bs;
            int bconv = conv[bs];
            unsigned ps = (bstart == 1) ? S32[lane] : N32[(bstart - 1) * WPR + lane];
            unsigned cs = S32[bstart * WPR + lane];
            ull cs_lsb = __ballot(cs & 1u);
            for (int r = bstart; r < bconv; ++r) {
                unsigned ns = S32[(r + 1) * WPR + lane];
                unsigned wk = W32[r * WPR + lane];
                ull ns_lsb = __ballot(ns & 1u);
                ull ns_msb = __ballot(ns >> 31);
                RowCtx c = make_ctx(cs, cs_lsb, ns, ns_lsb, ns_msb, wk, interior, lane);
                unsigned x = rowstep(ps, c, lane);
                N32[r * WPR + lane] = x;
                ps = x;
                cs = ns;
                cs_lsb = ns_lsb;
            }
        }
    }
}

// ---------------- Phase 4: materialize fp32 output ----------------
__global__ void expand_kernel(const ull* __restrict__ Ng,
                              const ull* __restrict__ Sg,
                              const ull* __restrict__ Wg,
                              float4* __restrict__ out) {
    int tid = blockIdx.x * blockDim.x + threadIdx.x;
    int p = tid << 2;
    int row = p >> 11;
    int colbase = p & 2047;
    bool edge = (row == 0) || (row == 2047);
    const ull* src = edge ? Sg : Ng;          // edge rows pass through t
    ull sw = src[p >> 6];
    ull ww = Wg[p >> 6];
    int bit = p & 63;
    float4 o;
    float* po = (float*)&o;
#pragma unroll
    for (int k = 0; k < 4; ++k) {
        int b = bit + k;
        bool sn = (sw >> b) & 1ull;
        bool wb = (ww >> b) & 1ull;
        int col = colbase + k;
        bool keep25 = wb && (edge || col == 0 || col == 2047);
        po[k] = sn ? 255.0f : (keep25 ? 25.0f : 0.0f);
    }
    out[tid] = o;
}

extern "C" void kernel_launch(void* const* d_in, const int* in_sizes, int n_in,
                              void* d_out, int out_size, void* d_ws, size_t ws_size,
                              hipStream_t stream) {
    const float* img = (const float*)d_in[0];
    char* ws = (char*)d_ws;
    unsigned* maxbits = (unsigned*)ws;                       // 4 B
    int* conv = (int*)(ws + 64);                             // 1 KiB
    ull* S    = (ull*)(ws + 2048);                           // 512 KiB
    ull* Wk   = (ull*)(ws + 2048 + (1 << 19));               // 512 KiB
    ull* Snew = (ull*)(ws + 2048 + (1 << 20));               // 512 KiB

    hipMemsetAsync(d_ws, 0, 4, stream);  // zero the atomicMax cell

    max_kernel<<<1024, 256, 0, stream>>>((const float4*)img, maxbits);
    binarize_kernel<<<(IMG_H * IMG_W) / 256, 256, 0, stream>>>(img, maxbits, S, Wk);
    spec_kernel<<<NSTRIPES, 64, 0, stream>>>((const unsigned*)S, (const unsigned*)Wk,
                                             (unsigned*)Snew, conv);
    fix_kernel<<<1, 64, 0, stream>>>((const unsigned*)S, (const unsigned*)Wk,
                                     (unsigned*)Snew, conv);
    expand_kernel<<<(IMG_H * IMG_W / 4) / 256, 256, 0, stream>>>(Snew, S, Wk, (float4*)d_out);
}

// Round 3
// 88.209 us; speedup vs baseline: 11.5037x; 1.5032x over previous
//
#include <hip/hip_runtime.h>

#define IMG_H 2048
#define IMG_W 2048
#define WPR 64       // 32-bit words per row
#define RSTRIPE 8
#define NSTRIPES 256 // covers rows 1..2046
#define MAXBLOCKS 256

typedef unsigned long long ull;

__device__ __forceinline__ unsigned interior_mask(int lane) {
    unsigned m = 0xffffffffu;
    if (lane == 0)  m &= ~1u;
    if (lane == 63) m &= 0x7fffffffu;
    return m;
}

struct RowCtx {
    unsigned b1, b2, b4, b8, b16, lowrun, a_static;
    ull B1, B2, B4, B8, B16, B32;
};

// ps-independent per-row precompute (shared between speculative chains)
__device__ __forceinline__ RowCtx make_ctx(unsigned cs, ull cs_lsb,
                                           unsigned ns, ull ns_lsb, ull ns_msb,
                                           unsigned wk, unsigned interior, int lane) {
    RowCtx c;
    c.b1 = wk & interior;
    unsigned rcs = (cs >> 1) | (((unsigned)((cs_lsb >> 1 >> lane) & 1ull)) << 31);
    unsigned rns = (ns >> 1) | (((unsigned)((ns_lsb >> 1 >> lane) & 1ull)) << 31);
    unsigned lns = (ns << 1) | ((unsigned)(((ns_msb << 1) >> lane) & 1ull));
    c.a_static = cs | (c.b1 & (rcs | lns | ns | rns));
    c.b2  = c.b1 & (c.b1 << 1);
    c.b4  = c.b2 & (c.b2 << 2);
    c.b8  = c.b4 & (c.b4 << 4);
    c.b16 = c.b8 & (c.b8 << 8);
    c.lowrun = c.b1 & (c.b1 ^ (c.b1 + 1u));   // low all-ones run of b1
    c.B1  = __ballot(c.b1 == 0xffffffffu);    // word fully propagates
    c.B2  = c.B1  & (c.B1  << 1);
    c.B4  = c.B2  & (c.B2  << 2);
    c.B8  = c.B4  & (c.B4  << 4);
    c.B16 = c.B8  & (c.B8  << 8);
    c.B32 = c.B16 & (c.B16 << 16);
    return c;
}

// one row of the recurrence: x[j] = a[j] | (b[j] & x[j-1]) closure, bit-parallel
__device__ __forceinline__ unsigned rowstep(unsigned ps, const RowCtx& c, int lane) {
    ull ps_msb = __ballot(ps >> 31);
    ull ps_lsb = __ballot(ps & 1u);
    unsigned lps = (ps << 1) | ((unsigned)(((ps_msb << 1) >> lane) & 1ull));
    unsigned rps = (ps >> 1) | (((unsigned)((ps_lsb >> 1 >> lane) & 1ull)) << 31);
    unsigned x = c.a_static | (c.b1 & (lps | ps | rps));
    x |= c.b1  & (x << 1);
    x |= c.b2  & (x << 2);
    x |= c.b4  & (x << 4);
    x |= c.b8  & (x << 8);
    x |= c.b16 & (x << 16);
    ull X = __ballot(x >> 31);
    X |= c.B1  & (X << 1);
    X |= c.B2  & (X << 2);
    X |= c.B4  & (X << 4);
    X |= c.B8  & (X << 8);
    X |= c.B16 & (X << 16);
    X |= c.B32 & (X << 32);
    unsigned carry = (unsigned)(((X << 1) >> lane) & 1ull);
    x |= carry ? c.lowrun : 0u;
    return x;
}

// ---------------- Phase 1a: per-block max partials (no atomics) -------------
__global__ __launch_bounds__(256) void max_part_kernel(const float4* __restrict__ in,
                                                       float* __restrict__ partial) {
    __shared__ float sm[4];
    int tid = blockIdx.x * blockDim.x + threadIdx.x;
    int stride = gridDim.x * blockDim.x;
    float m = 0.0f;
    for (int i = tid; i < (IMG_H * IMG_W / 4); i += stride) {
        float4 v = in[i];
        m = fmaxf(fmaxf(m, v.x), fmaxf(v.y, fmaxf(v.z, v.w)));
    }
#pragma unroll
    for (int off = 32; off > 0; off >>= 1)
        m = fmaxf(m, __shfl_down(m, off, 64));
    if ((threadIdx.x & 63) == 0) sm[threadIdx.x >> 6] = m;
    __syncthreads();
    if (threadIdx.x == 0)
        partial[blockIdx.x] = fmaxf(fmaxf(sm[0], sm[1]), fmaxf(sm[2], sm[3]));
}

// ---------------- Phase 1b: reduce partials -> final max --------------------
__global__ __launch_bounds__(256) void max_final_kernel(const float* __restrict__ partial,
                                                        float* __restrict__ maxv) {
    __shared__ float sm[4];
    float m = partial[threadIdx.x];
#pragma unroll
    for (int off = 32; off > 0; off >>= 1)
        m = fmaxf(m, __shfl_down(m, off, 64));
    if ((threadIdx.x & 63) == 0) sm[threadIdx.x >> 6] = m;
    __syncthreads();
    if (threadIdx.x == 0)
        *maxv = fmaxf(fmaxf(sm[0], sm[1]), fmaxf(sm[2], sm[3]));
}

// ---------------- Phase 2: classify -> bitmasks ----------------
__global__ void binarize_kernel(const float* __restrict__ img,
                                const float* __restrict__ maxptr,
                                ull* __restrict__ S, ull* __restrict__ Wk) {
    int tid = blockIdx.x * blockDim.x + threadIdx.x;
    float maxv = *maxptr;
    float high = maxv * 0.15f;
    float low  = high * 0.05f;
    float x = img[tid];
    ull sb = __ballot(x > high);
    ull wb = __ballot((x >= low) && (x <= high));
    if ((threadIdx.x & 63) == 0) {
        S[tid >> 6]  = sb;
        Wk[tid >> 6] = wb;
    }
}

// ---------------- Phase 3a: parallel speculative stripes ----------------
// Each block handles RSTRIPE rows with lower (ps=S[prev]) and upper
// (ps=S[prev]|W[prev]&interior) bounds. Monotonicity => first row where
// bounds agree is exact; all later rows in the stripe are exact.
__global__ __launch_bounds__(64) void spec_kernel(const unsigned* __restrict__ S32,
                                                  const unsigned* __restrict__ W32,
                                                  unsigned* __restrict__ N32,
                                                  int* __restrict__ conv) {
    const int s = blockIdx.x;
    const int lane = threadIdx.x;
    const int start = 1 + RSTRIPE * s;
    const int end = min(start + RSTRIPE, 2047);  // exclusive
    const unsigned interior = interior_mask(lane);

    // preload whole stripe (independent loads, one latency)
    unsigned pcs = S32[(start - 1) * WPR + lane];
    unsigned pw  = W32[(start - 1) * WPR + lane];
    unsigned csb[RSTRIPE + 1], wkb[RSTRIPE];
#pragma unroll
    for (int u = 0; u <= RSTRIPE; ++u)
        csb[u] = S32[min(start + u, 2047) * WPR + lane];
#pragma unroll
    for (int u = 0; u < RSTRIPE; ++u)
        wkb[u] = W32[min(start + u, 2046) * WPR + lane];

    unsigned psl = pcs;
    unsigned psu = (start == 1) ? pcs : (pcs | (pw & interior));  // row 0 is exact
    unsigned cs = csb[0];
    ull cs_lsb = __ballot(cs & 1u);
    int conv_r = end;           // sentinel: nothing exact in stripe
    bool converged = false;
#pragma unroll
    for (int u = 0; u < RSTRIPE; ++u) {
        const int r = start + u;
        if (r < 2047) {                       // uniform guard
            unsigned ns = csb[u + 1];
            unsigned wk = wkb[u];
            ull ns_lsb = __ballot(ns & 1u);
            ull ns_msb = __ballot(ns >> 31);
            RowCtx c = make_ctx(cs, cs_lsb, ns, ns_lsb, ns_msb, wk, interior, lane);
            unsigned xu = rowstep(psu, c, lane);
            unsigned xl;
            if (!converged) {                 // uniform
                xl = rowstep(psl, c, lane);
                if (__ballot(xl != xu) == 0ull) { converged = true; conv_r = r; }
            } else {
                xl = xu;
            }
            N32[r * WPR + lane] = xu;
            psl = xl;
            psu = xu;
            cs = ns;
            cs_lsb = ns_lsb;
        }
    }
    if (lane == 0) conv[s] = conv_r;
}

// ---------------- Phase 3b: sequential fix-up of unconverged prefixes -------
__global__ __launch_bounds__(64) void fix_kernel(const unsigned* __restrict__ S32,
                                                 const unsigned* __restrict__ W32,
                                                 unsigned* N32,
                                                 const int* __restrict__ conv) {
    const int lane = threadIdx.x;
    const unsigned interior = interior_mask(lane);
    for (int g = 0; g < NSTRIPES / 64; ++g) {
        int s = g * 64 + lane;
        int start0 = 1 + RSTRIPE * s;
        int cv = conv[s];
        ull bad = __ballot(cv > start0);
        while (bad) {                         // uniform loop, ascending order
            int idx = __ffsll(bad) - 1;
            bad &= bad - 1;
            int bs = g * 64 + idx;
            int bstart = 1 + RSTRIPE * bs;
            int bconv = conv[bs];
            unsigned ps = (bstart == 1) ? S32[lane] : N32[(bstart - 1) * WPR + lane];
            unsigned cs = S32[bstart * WPR + lane];
            ull cs_lsb = __ballot(cs & 1u);
            for (int r = bstart; r < bconv; ++r) {
                unsigned ns = S32[(r + 1) * WPR + lane];
                unsigned wk = W32[r * WPR + lane];
                ull ns_lsb = __ballot(ns & 1u);
                ull ns_msb = __ballot(ns >> 31);
                RowCtx c = make_ctx(cs, cs_lsb, ns, ns_lsb, ns_msb, wk, interior, lane);
                unsigned x = rowstep(ps, c, lane);
                N32[r * WPR + lane] = x;
                ps = x;
                cs = ns;
                cs_lsb = ns_lsb;
            }
        }
    }
}

// ---------------- Phase 4: materialize fp32 output ----------------
__global__ void expand_kernel(const ull* __restrict__ Ng,
                              const ull* __restrict__ Sg,
                              const ull* __restrict__ Wg,
                              float4* __restrict__ out) {
    int tid = blockIdx.x * blockDim.x + threadIdx.x;
    int p = tid << 2;
    int row = p >> 11;
    int colbase = p & 2047;
    bool edge = (row == 0) || (row == 2047);
    const ull* src = edge ? Sg : Ng;          // edge rows pass through t
    ull sw = src[p >> 6];
    ull ww = Wg[p >> 6];
    int bit = p & 63;
    float4 o;
    float* po = (float*)&o;
#pragma unroll
    for (int k = 0; k < 4; ++k) {
        int b = bit + k;
        bool sn = (sw >> b) & 1ull;
        bool wb = (ww >> b) & 1ull;
        int col = colbase + k;
        bool keep25 = wb && (edge || col == 0 || col == 2047);
        po[k] = sn ? 255.0f : (keep25 ? 25.0f : 0.0f);
    }
    out[tid] = o;
}

extern "C" void kernel_launch(void* const* d_in, const int* in_sizes, int n_in,
                              void* d_out, int out_size, void* d_ws, size_t ws_size,
                              hipStream_t stream) {
    const float* img = (const float*)d_in[0];
    char* ws = (char*)d_ws;
    float* maxv = (float*)ws;                                // 4 B
    int* conv = (int*)(ws + 64);                             // 1 KiB
    float* partial = (float*)(ws + 1024 + 64);               // 1 KiB
    ull* S    = (ull*)(ws + 4096);                           // 512 KiB
    ull* Wk   = (ull*)(ws + 4096 + (1 << 19));               // 512 KiB
    ull* Snew = (ull*)(ws + 4096 + (1 << 20));               // 512 KiB

    max_part_kernel<<<MAXBLOCKS, 256, 0, stream>>>((const float4*)img, partial);
    max_final_kernel<<<1, 256, 0, stream>>>(partial, maxv);
    binarize_kernel<<<(IMG_H * IMG_W) / 256, 256, 0, stream>>>(img, maxv, S, Wk);
    spec_kernel<<<NSTRIPES, 64, 0, stream>>>((const unsigned*)S, (const unsigned*)Wk,
                                             (unsigned*)Snew, conv);
    fix_kernel<<<1, 64, 0, stream>>>((const unsigned*)S, (const unsigned*)Wk,
                                     (unsigned*)Snew, conv);
    expand_kernel<<<(IMG_H * IMG_W / 4) / 256, 256, 0, stream>>>(Snew, S, Wk, (float4*)d_out);
}